// Round 1
// baseline (2196.123 us; speedup 1.0000x reference)
//
#include <hip/hip_runtime.h>
#include <hip/hip_bf16.h>

#define NST 512
#define TMAX 256
#define NBATCH 64
#define MVOC 32000

// ---------- block-wide reductions (512 threads = 8 waves) ----------
// Each helper is internally synchronized: sync before writing the shared
// scratch (protects previous consumer) and after (protects the read).
__device__ __forceinline__ float block_max(float v, float* red) {
#pragma unroll
    for (int off = 32; off; off >>= 1) v = fmaxf(v, __shfl_xor(v, off, 64));
    __syncthreads();
    if ((threadIdx.x & 63) == 0) red[threadIdx.x >> 6] = v;
    __syncthreads();
    float m = red[0];
#pragma unroll
    for (int k = 1; k < 8; ++k) m = fmaxf(m, red[k]);
    return m;
}

__device__ __forceinline__ float block_sum(float v, float* red) {
#pragma unroll
    for (int off = 32; off; off >>= 1) v += __shfl_xor(v, off, 64);
    __syncthreads();
    if ((threadIdx.x & 63) == 0) red[threadIdx.x >> 6] = v;
    __syncthreads();
    float s = red[0];
#pragma unroll
    for (int k = 1; k < 8; ++k) s += red[k];
    return s;
}

// ---------- prep: column sums of exp(trans) ----------
// trans is (NST, NST) row-major; softmax over axis 0 (rows) per column j.
__global__ void k_colsum(const float* __restrict__ trans, float* __restrict__ inv) {
    int j = threadIdx.x;  // one block of 512 threads, thread = column
    float s = 0.f;
    for (int i = 0; i < NST; ++i) s += expf(trans[i * NST + j]);
    inv[j] = 1.f / s;
}

// ---------- prep: W[i][j] = exp(trans[i][j]) / colsum[j], stored bf16 ----------
__global__ void k_buildW(const float* __restrict__ trans, const float* __restrict__ inv,
                         __hip_bfloat16* __restrict__ W) {
    int idx = blockIdx.x * NST + threadIdx.x;   // row = blockIdx, col = tid
    float w = expf(trans[idx]) * inv[threadIdx.x];
    W[idx] = __float2bfloat16(w);
}

// ---------- main: one block per batch, sequential recurrence ----------
__global__ void __launch_bounds__(512) k_forward(
    const int* __restrict__ x, const int* __restrict__ Tlen,
    const float* __restrict__ priors, const float* __restrict__ emit,
    const __hip_bfloat16* __restrict__ W, float* __restrict__ out) {
    __shared__ float p[NST];
    __shared__ float red[8];

    const int b = blockIdx.x;
    const int j = threadIdx.x;

    // priors log-softmax (each block redundantly; 512 elems, trivial)
    float pr = priors[j];
    float pm = block_max(pr, red);
    float ps = block_sum(expf(pr - pm), red);
    float prior_log = pr - pm - logf(ps);

    // e0[b][j] = log_softmax(emit[:, x[b,0]], over states)[j]
    const int m0 = x[b * TMAX];              // x[b, 0]
    float em = emit[j * MVOC + m0];          // emit[j][m0]
    float emx = block_max(em, red);
    float ems = block_sum(expf(em - emx), red);
    float e0 = em - emx - logf(ems);

    float alpha = e0 + prior_log;            // log_alpha0[b][j]
    const int Tb = Tlen[b];

    for (int t = 1; t < Tb; ++t) {
        // renormalize: p[i] = exp(alpha_i - max)
        float mx = block_max(alpha, red);    // internal syncs also protect p[] reuse
        p[j] = expf(alpha - mx);
        __syncthreads();

        // s_j = sum_i p[i] * W[i][j]  (coalesced: lane j reads column j)
        float s = 0.f;
        const __hip_bfloat16* Wc = W + j;
        const float4* p4 = (const float4*)p;
#pragma unroll 4
        for (int i4 = 0; i4 < NST / 4; ++i4) {
            float4 pv = p4[i4];              // LDS broadcast, 16B
            int i = i4 * 4;
            s += pv.x * __bfloat162float(Wc[(i + 0) * NST]);
            s += pv.y * __bfloat162float(Wc[(i + 1) * NST]);
            s += pv.z * __bfloat162float(Wc[(i + 2) * NST]);
            s += pv.w * __bfloat162float(Wc[(i + 3) * NST]);
        }
        alpha = e0 + mx + logf(s);
    }

    // answer = logsumexp_j(alpha)
    float mx = block_max(alpha, red);
    float s = block_sum(expf(alpha - mx), red);
    if (j == 0) out[b] = mx + logf(s);
}

extern "C" void kernel_launch(void* const* d_in, const int* in_sizes, int n_in,
                              void* d_out, int out_size, void* d_ws, size_t ws_size,
                              hipStream_t stream) {
    const int* x = (const int*)d_in[0];          // (64, 256) int32
    const int* T = (const int*)d_in[1];          // (64,) int32
    const float* priors = (const float*)d_in[2]; // (512,)
    const float* trans = (const float*)d_in[3];  // (512, 512)
    const float* emit = (const float*)d_in[4];   // (512, 32000)
    float* out = (float*)d_out;                  // (64,) f32

    float* inv = (float*)d_ws;                                       // 2 KB
    __hip_bfloat16* W = (__hip_bfloat16*)((char*)d_ws + 4096);       // 512 KB

    k_colsum<<<1, NST, 0, stream>>>(trans, inv);
    k_buildW<<<NST, NST, 0, stream>>>(trans, inv, W);
    k_forward<<<NBATCH, NST, 0, stream>>>(x, T, priors, emit, W, out);
}

// Round 2
// 479.101 us; speedup vs baseline: 4.5838x; 4.5838x over previous
//
#include <hip/hip_runtime.h>
#include <hip/hip_bf16.h>
#include <hip/hip_fp16.h>

#define NST 512
#define TMAX 256
#define NBATCH 64
#define MVOC 32000

typedef float f32x4 __attribute__((ext_vector_type(4)));

// ---------- block-wide reductions (512 threads = 8 waves) ----------
__device__ __forceinline__ float block_max(float v, float* red) {
#pragma unroll
    for (int off = 32; off; off >>= 1) v = fmaxf(v, __shfl_xor(v, off, 64));
    __syncthreads();
    if ((threadIdx.x & 63) == 0) red[threadIdx.x >> 6] = v;
    __syncthreads();
    float m = red[0];
#pragma unroll
    for (int k = 1; k < 8; ++k) m = fmaxf(m, red[k]);
    return m;
}

__device__ __forceinline__ float block_sum(float v, float* red) {
#pragma unroll
    for (int off = 32; off; off >>= 1) v += __shfl_xor(v, off, 64);
    __syncthreads();
    if ((threadIdx.x & 63) == 0) red[threadIdx.x >> 6] = v;
    __syncthreads();
    float s = red[0];
#pragma unroll
    for (int k = 1; k < 8; ++k) s += red[k];
    return s;
}

// f32 -> OCP e5m2 (bf8), round-nearest-even via the f16 path
__device__ __forceinline__ unsigned char f32_to_e5m2(float v) {
    unsigned short hb = __half_as_ushort(__float2half(v));
    unsigned short r = (unsigned short)((hb + 0x7F + ((hb >> 8) & 1)) >> 8);
    return (unsigned char)r;
}

// ---------- prep 1: per-column max and lc[j] = log(colmax of softmax col) ----------
// trans (NST,NST) row-major, softmax over axis 0 (rows) per column j.
__global__ void k_prep(const float* __restrict__ trans,
                       float* __restrict__ tmax, float* __restrict__ lc) {
    int j = threadIdx.x;           // one block, 512 threads, thread = column
    float m = -1e30f, s = 0.f;
    for (int i = 0; i < NST; ++i) {
        float t = trans[i * NST + j];          // coalesced
        float nm = fmaxf(m, t);
        s = s * __expf(m - nm) + __expf(t - nm);
        m = nm;
    }
    tmax[j] = m;
    lc[j] = -logf(s);              // log(cmax_j) = tmax_j - lse_j = -log(sum exp(t-tmax))
}

// ---------- prep 2: WT8[j][i] = e5m2( exp(trans[i][j] - tmax[j]) )  (transposed) ----------
__global__ void k_buildW8(const float* __restrict__ trans, const float* __restrict__ tmax,
                          unsigned char* __restrict__ WT8) {
    int i = blockIdx.x;            // row of trans
    int j = threadIdx.x;           // column
    float v = __expf(trans[i * NST + j] - tmax[j]);   // coalesced read
    WT8[j * NST + i] = f32_to_e5m2(v);                // scattered byte write (one-time)
}

// ---------- main: one block per batch, bf8-MFMA matvec recurrence ----------
__global__ void __launch_bounds__(512) k_forward(
    const int* __restrict__ x, const int* __restrict__ Tlen,
    const float* __restrict__ priors, const float* __restrict__ emit,
    const unsigned char* __restrict__ WT8, const float* __restrict__ lc,
    float* __restrict__ out) {
    __shared__ unsigned long long p8q[NST / 8];   // 512 bytes of e5m2 p
    __shared__ float svec[NST];
    __shared__ float red[8];

    const int b = blockIdx.x;
    const int j = threadIdx.x;
    const int w = j >> 6;          // wave 0..7
    const int l = j & 63;          // lane

    // priors log-softmax
    float pr = priors[j];
    float pm = block_max(pr, red);
    float ps = block_sum(__expf(pr - pm), red);
    float prior_log = pr - pm - logf(ps);

    // e0[b][j] = log_softmax(emit[:, x[b,0]])[j]
    const int m0 = x[b * TMAX];
    float em = emit[(long)j * MVOC + m0];
    float emx = block_max(em, red);
    float ems = block_sum(__expf(em - emx), red);
    float e0 = em - emx - logf(ems);

    float alpha = e0 + prior_log;
    const float ecol = e0 + lc[j];
    const int Tb = Tlen[b];

    // B-operand base, in 8-byte units: col*(NST/8) + (l>>4); col = w*64 + (l&15)
    const unsigned long long* WT8q = (const unsigned long long*)WT8;
    const unsigned long long* wbase = WT8q + (unsigned long long)(w * 64 + (l & 15)) * (NST / 8) + (l >> 4);
    const bool arow0 = ((l & 15) == 0);

    for (int t = 1; t < Tb; ++t) {
        float mx = block_max(alpha, red);               // 2 syncthreads inside
        ((unsigned char*)p8q)[j] = f32_to_e5m2(__expf(alpha - mx));
        __syncthreads();

        f32x4 acc0 = {0.f, 0.f, 0.f, 0.f};
        f32x4 acc1 = acc0, acc2 = acc0, acc3 = acc0;
#pragma unroll
        for (int kt = 0; kt < 16; ++kt) {
            // A-frag: row = l&15 (only row 0 non-zero), k = kt*32 + (l>>4)*8 .. +7
            unsigned long long a = arow0 ? p8q[kt * 4 + (l >> 4)] : 0ULL;
            // B-frags for the wave's 4 column tiles (stride 16 cols = 16*64 qwords)
            unsigned long long b0 = wbase[kt * 4];
            unsigned long long b1 = wbase[1024 + kt * 4];
            unsigned long long b2 = wbase[2048 + kt * 4];
            unsigned long long b3 = wbase[3072 + kt * 4];
            acc0 = __builtin_amdgcn_mfma_f32_16x16x32_bf8_bf8((long)a, (long)b0, acc0, 0, 0, 0);
            acc1 = __builtin_amdgcn_mfma_f32_16x16x32_bf8_bf8((long)a, (long)b1, acc1, 0, 0, 0);
            acc2 = __builtin_amdgcn_mfma_f32_16x16x32_bf8_bf8((long)a, (long)b2, acc2, 0, 0, 0);
            acc3 = __builtin_amdgcn_mfma_f32_16x16x32_bf8_bf8((long)a, (long)b3, acc3, 0, 0, 0);
        }
        // C row 0 lives in lanes 0..15, register 0
        if (l < 16) {
            svec[w * 64 + 0 * 16 + l] = acc0[0];
            svec[w * 64 + 1 * 16 + l] = acc1[0];
            svec[w * 64 + 2 * 16 + l] = acc2[0];
            svec[w * 64 + 3 * 16 + l] = acc3[0];
        }
        __syncthreads();

        float s = fmaxf(svec[j], 1e-37f);
        alpha = ecol + mx + logf(s);
    }

    float mx = block_max(alpha, red);
    float s = block_sum(__expf(alpha - mx), red);
    if (j == 0) out[b] = mx + logf(s);
}

extern "C" void kernel_launch(void* const* d_in, const int* in_sizes, int n_in,
                              void* d_out, int out_size, void* d_ws, size_t ws_size,
                              hipStream_t stream) {
    const int* x = (const int*)d_in[0];          // (64, 256) int32
    const int* T = (const int*)d_in[1];          // (64,) int32
    const float* priors = (const float*)d_in[2]; // (512,)
    const float* trans = (const float*)d_in[3];  // (512, 512)
    const float* emit = (const float*)d_in[4];   // (512, 32000)
    float* out = (float*)d_out;                  // (64,) f32

    float* tmax = (float*)d_ws;                                   // 2 KB
    float* lc = (float*)((char*)d_ws + 4096);                     // 2 KB
    unsigned char* WT8 = (unsigned char*)d_ws + 8192;             // 256 KB, transposed W in e5m2

    k_prep<<<1, NST, 0, stream>>>(trans, tmax, lc);
    k_buildW8<<<NST, NST, 0, stream>>>(trans, tmax, WT8);
    k_forward<<<NBATCH, NST, 0, stream>>>(x, T, priors, emit, WT8, lc, out);
}